// Round 18
// baseline (154.605 us; speedup 1.0000x reference)
//
#include <hip/hip_runtime.h>
#include <stdint.h>
#include <stddef.h>

// Problem constants
#define SEQ   512
#define HID   512
#define NHEAD 8
#define HD    64
#define NBATCH 16
#define NTOK  8192      // NBATCH*SEQ
#define MAXD  10
#define LOG2E 1.4426950408889634f

typedef __attribute__((ext_vector_type(8))) short short8;
typedef __attribute__((ext_vector_type(4))) float f32x4;

typedef __attribute__((address_space(3))) void        as3_void;
typedef const __attribute__((address_space(1))) void  as1_cvoid;

#define MFMA16(a,b,c) __builtin_amdgcn_mfma_f32_16x16x32_bf16((a),(b),(c),0,0,0)

__device__ __forceinline__ float bf2f(uint16_t u){ return __uint_as_float(((uint32_t)u)<<16); }
__device__ __forceinline__ uint16_t f2bf(float f){
  uint32_t i = __float_as_uint(f);
  return (uint16_t)((i + 0x7fffu + ((i>>16)&1u)) >> 16);
}
// truncating bf16 (P-pack only: P in (0,1], denominator exact -> bias < 0.4%)
__device__ __forceinline__ uint16_t f2bf_rtz(float f){
  return (uint16_t)(__float_as_uint(f) >> 16);
}

enum { EPI_BF16=0, EPI_F32=3, EPI_RELU=4 };

// ---------------------------------------------------------------------------
// prep: weight transpose+convert (blocks 0..3071) and x fp32->bf16
// (blocks 3072..7167) merged into one launch.
// ---------------------------------------------------------------------------
__global__ __launch_bounds__(256) void prep_kernel(
    const float* __restrict__ x, uint16_t* __restrict__ xb,
    const float* __restrict__ Wq, const float* __restrict__ Wk,
    const float* __restrict__ Wv, const float* __restrict__ Wo,
    const float* __restrict__ W1, const float* __restrict__ W2,
    uint16_t* __restrict__ tq, uint16_t* __restrict__ tk,
    uint16_t* __restrict__ tv, uint16_t* __restrict__ to_,
    uint16_t* __restrict__ t1, uint16_t* __restrict__ t2)
{
  int id = blockIdx.x;
  if (id >= 3072){                       // ---- f2bf part ----
    int i = (id-3072)*256 + threadIdx.x;
    if (i < NTOK*HID/4){
      float4 v = *(const float4*)(x + (size_t)i*4);
      *(ushort4*)(xb + (size_t)i*4) =
          make_ushort4(f2bf(v.x), f2bf(v.y), f2bf(v.z), f2bf(v.w));
    }
    return;
  }
  // ---- transpose part ----
  __shared__ uint16_t tile[32][33];
  const float* in; uint16_t* out; int R, C, tx, ty;
  if (id < 1024) {
    int m = id >> 8, loc = id & 255;
    in  = (m==0)?Wq:(m==1)?Wk:(m==2)?Wv:Wo;
    out = (m==0)?tq:(m==1)?tk:(m==2)?tv:to_;
    R = 512; C = 512; ty = loc>>4; tx = loc&15;
  } else if (id < 2048) {
    int loc = id-1024; in=W1; out=t1; R=512; C=2048; ty=loc>>6; tx=loc&63;
  } else {
    int loc = id-2048; in=W2; out=t2; R=2048; C=512; ty=loc>>4; tx=loc&15;
  }
  int bx = tx*32, by = ty*32;
  int lx = threadIdx.x & 31, ly = threadIdx.x >> 5;   // 32x8
  #pragma unroll
  for (int i=ly; i<32; i+=8) tile[i][lx] = f2bf(in[(size_t)(by+i)*C + bx+lx]);
  __syncthreads();
  #pragma unroll
  for (int i=ly; i<32; i+=8) out[(size_t)(bx+i)*R + by+lx] = tile[lx][i];
}

// ---------------------------------------------------------------------------
// GEMM mainloop — 2-phase double-buffer; T2 swizzle (rule #21).
// ---------------------------------------------------------------------------
template<int BM, int BN>
__device__ __forceinline__ void gemm_tile_mainloop(
    const uint16_t* __restrict__ A, const uint16_t* __restrict__ Bt,
    int K, int m0, int n0, uint16_t* lA, uint16_t* lB,
    f32x4 acc[4][(BM==128)?4:((BN==128)?2:1)])
{
  constexpr int NJ  = (BM==128)?4:((BN==128)?2:1);
  constexpr int ARD = BM/32;
  constexpr int BRD = BN/32;
  const int t = threadIdx.x;
  const int w = t>>6, l = t&63;
  const int lg = l>>4, lc = l&15;
  const int wr = (BM==128)?(w>>1):0;
  const int wc = (BM==128)?(w&1):w;
  const int swz = lc & 7;                  // read-side chunk XOR
  const int kSteps = K>>6;

  auto stage = [&](int kt, int buf){
    const int k0 = kt<<6;
    #pragma unroll
    for (int rd=0; rd<ARD; ++rd){
      const int e   = rd*2048 + t*8;
      const int row = e>>6;
      const int col = (((e>>3)&7) ^ (row&7))*8;   // inverse-swizzled source
      const uint16_t* ga = A + (size_t)(m0+row)*K + (k0+col);
      char* la = (char*)(lA + buf*(BM*64)) + rd*4096 + w*1024;
      __builtin_amdgcn_global_load_lds((as1_cvoid*)ga, (as3_void*)la, 16, 0, 0);
    }
    #pragma unroll
    for (int rd=0; rd<BRD; ++rd){
      const int e   = rd*2048 + t*8;
      const int row = e>>6;
      const int col = (((e>>3)&7) ^ (row&7))*8;
      const uint16_t* gb = Bt + (size_t)(n0+row)*K + (k0+col);
      char* lb = (char*)(lB + buf*(BN*64)) + rd*4096 + w*1024;
      __builtin_amdgcn_global_load_lds((as1_cvoid*)gb, (as3_void*)lb, 16, 0, 0);
    }
  };

  auto compute = [&](const uint16_t* rA, const uint16_t* rB){
    #pragma unroll
    for (int kk=0; kk<2; ++kk){
      const int cc = (kk*4 + lg) ^ swz;      // swizzled read chunk
      short8 af[4], bfr[NJ];
      #pragma unroll
      for (int i=0;i<4;i++)
        af[i]  = *(const short8*)&rA[(wr*64 + i*16 + lc)*64 + cc*8];
      #pragma unroll
      for (int j=0;j<NJ;j++)
        bfr[j] = *(const short8*)&rB[(wc*16*NJ + j*16 + lc)*64 + cc*8];
      #pragma unroll
      for (int i=0;i<4;i++)
        #pragma unroll
        for (int j=0;j<NJ;j++)
          acc[i][j] = MFMA16(af[i], bfr[j], acc[i][j]);
    }
  };

  stage(0, 0);
  __syncthreads();                   // drain prologue loads
  int cur = 0;
  for (int kt=0; kt<kSteps; ++kt){
    if (kt+1 < kSteps) stage(kt+1, cur^1);   // issue next tile early
    compute(lA + cur*(BM*64), lB + cur*(BN*64));
    __syncthreads();                 // drains next-tile loads + read fence
    cur ^= 1;
  }
}

// Generic GEMM with epilogue template (bias fp32). Grid: x=m-tile, y=n-tile.
template<int EPI, int BM, int BN>
__global__ __launch_bounds__(256,2) void gemm_bt(
    const uint16_t* __restrict__ A, const uint16_t* __restrict__ Bt,
    const float* __restrict__ bias, void* __restrict__ outp,
    int M, int N, int K)
{
  constexpr int NJ = (BM==128)?4:((BN==128)?2:1);
  __shared__ uint16_t lA[2*BM*64];
  __shared__ uint16_t lB[2*BN*64];
  f32x4 acc[4][NJ];
  #pragma unroll
  for (int i=0;i<4;i++)
    #pragma unroll
    for (int j=0;j<NJ;j++){ f32x4 z = {0.f,0.f,0.f,0.f}; acc[i][j]=z; }
  const int m0 = blockIdx.x*BM, n0 = blockIdx.y*BN;
  gemm_tile_mainloop<BM,BN>(A, Bt, K, m0, n0, lA, lB, acc);

  const int t=threadIdx.x, w=t>>6, l=t&63, lg=l>>4, lc=l&15;
  const int wr=(BM==128)?(w>>1):0, wc=(BM==128)?(w&1):w;
  #pragma unroll
  for (int j=0;j<NJ;j++){
    const int col = n0 + wc*16*NJ + j*16 + lc;
    const float bs = bias[col];
    #pragma unroll
    for (int i=0;i<4;i++){
      const int rowb = m0 + wr*64 + i*16 + lg*4;
      #pragma unroll
      for (int r=0;r<4;r++){
        float v = acc[i][j][r] + bs;
        if constexpr (EPI==EPI_RELU)   v = fmaxf(v, 0.f);
        if constexpr (EPI==EPI_F32)
          ((float*)outp)[(size_t)(rowb+r)*N + col] = v;
        else
          ((uint16_t*)outp)[(size_t)(rowb+r)*N + col] = f2bf(v);
      }
    }
  }
}

// ---------------------------------------------------------------------------
// Fused QKV + bias-pack mega-kernel (r16). Grid (64,4,4) = 1024 blocks.
// Every 4th block packs dist/edge/mask (memory-bound role overlapping the
// MFMA-bound GEMM roles); remaining 768 = r14 qkv GEMM (128² dbuf tiles).
// ---------------------------------------------------------------------------
__global__ __launch_bounds__(256,2) void qkv_pack(
    const uint16_t* __restrict__ x,
    const uint16_t* __restrict__ wtq, const uint16_t* __restrict__ wtk,
    const uint16_t* __restrict__ wtv,
    const float* __restrict__ bq, const float* __restrict__ bk,
    const float* __restrict__ bv,
    uint16_t* __restrict__ qo, uint16_t* __restrict__ kp,
    uint16_t* __restrict__ vp,
    const int*   __restrict__ dist,  // [16][512][512]
    const float* __restrict__ edge,  // [16][512][512]
    const int*   __restrict__ mask,  // [16][512]
    uint32_t*    __restrict__ biasp) // [16][32][8][64][16]
{
  __shared__ char smem[2*2*128*64*2];   // 64 KB union (gemm dbuf / pack stage)
  const int t = threadIdx.x;
  const int flat = blockIdx.x + 64*(blockIdx.y + 4*blockIdx.z);

  if ((flat & 3) == 3){
    // ---------------- pack role: two (b,it) units ----------------
    int*   dl = (int*)smem;                       // [16][260]
    float* el = (float*)(smem + 16*260*4);        // [16][260]
    int*   ml = (int*)(smem + 2*16*260*4);        // [512]
    #define DL(r,c) dl[(r)*260+(c)]
    #define EL(r,c) el[(r)*260+(c)]
    #pragma unroll
    for (int u0=0; u0<2; ++u0){
      const int u  = (flat>>2)*2 + u0;
      const int b  = u>>5, it = u&31;
      __syncthreads();                  // protect smem reuse across units
      ml[t]     = mask[b*SEQ + t];
      ml[t+256] = mask[b*SEQ + t + 256];
      #pragma unroll
      for (int jh=0; jh<2; ++jh){
        if (jh) __syncthreads();        // protect stage reuse across halves
        {
          const int r  = t >> 4;
          const int c0 = (t & 15) * 16;
          const size_t g = ((size_t)b*SEQ + it*16 + r)*SEQ + jh*256 + c0;
          *(int4*)&DL(r,c0)      = *(const int4*)&dist[g];
          *(int4*)&DL(r,c0+4)    = *(const int4*)&dist[g+4];
          *(int4*)&DL(r,c0+8)    = *(const int4*)&dist[g+8];
          *(int4*)&DL(r,c0+12)   = *(const int4*)&dist[g+12];
          *(float4*)&EL(r,c0)    = *(const float4*)&edge[g];
          *(float4*)&EL(r,c0+4)  = *(const float4*)&edge[g+4];
          *(float4*)&EL(r,c0+8)  = *(const float4*)&edge[g+8];
          *(float4*)&EL(r,c0+12) = *(const float4*)&edge[g+12];
        }
        __syncthreads();
        {
          const int i   = t & 15;
          const int j0p = (t >> 4) * 16;        // 16 consecutive j: one jn
          const int jn  = (j0p >> 4) & 3;
          const int jt  = jh*4 + (j0p >> 6);
          uint32_t wv[16];
          #pragma unroll
          for (int e=0; e<16; ++e){
            const int jl = j0p + e;
            const int jg = jh*256 + jl;
            const uint32_t d  = (uint32_t)DL(i,jl) & 0xFFu;
            const uint32_t mk = (ml[jg] ? 1u : 0u) << 8;
            wv[e] = ((uint32_t)f2bf(EL(i,jl)) << 16) | mk | d;
          }
          uint32_t* ob = biasp + ((((size_t)b*32 + it)*8 + jt)*64)*16;
          #pragma unroll
          for (int lgq=0; lgq<4; ++lgq)
            *(uint4*)&ob[(lgq*16 + i)*16 + jn*4] =
                make_uint4(wv[lgq*4], wv[lgq*4+1], wv[lgq*4+2], wv[lgq*4+3]);
        }
      }
    }
    #undef DL
    #undef EL
    return;
  }

  // ---------------- gemm role (r14 qkv) ----------------
  const int g  = (flat>>2)*3 + (flat&3);
  const int m0 = (g & 63) * 128;
  const int n0 = ((g >> 6) & 3) * 128;
  const int z  = g >> 8;
  uint16_t* lA = (uint16_t*)smem;
  uint16_t* lB = lA + 2*128*64;
  const uint16_t* Bt = (z==0)?wtq:(z==1)?wtk:wtv;
  const float*  bias = (z==0)?bq :(z==1)?bk :bv;
  f32x4 acc[4][4];
  #pragma unroll
  for (int i=0;i<4;i++)
    #pragma unroll
    for (int j=0;j<4;j++){ f32x4 zz = {0.f,0.f,0.f,0.f}; acc[i][j]=zz; }
  gemm_tile_mainloop<128,128>(x, Bt, HID, m0, n0, lA, lB, acc);

  const int w=t>>6, l=t&63, lg=l>>4, lc=l&15, wr=w>>1, wc=w&1;
  if (z==0){
    const float scale = 0.125f * LOG2E;   // 1/sqrt(HD) * log2(e)
    #pragma unroll
    for (int j=0;j<4;j++){
      const int col = n0 + wc*64 + j*16 + lc;
      const float bs = bias[col];
      #pragma unroll
      for (int i=0;i<4;i++){
        const int rowb = m0 + wr*64 + i*16 + lg*4;
        #pragma unroll
        for (int r=0;r<4;r++)
          qo[(size_t)(rowb+r)*HID + col] = f2bf((acc[i][j][r] + bs)*scale);
      }
    }
  } else if (z==1){
    // K fragment-packed: scalar stores, paid once.
    #pragma unroll
    for (int j=0;j<4;j++){
      const int col = n0 + wc*64 + j*16 + lc;
      const float bs = bias[col];
      const int h_ = col>>6, cm = col&63, kk = cm>>5, lgk = (cm>>3)&3, e = col&7;
      #pragma unroll
      for (int i=0;i<4;i++){
        const int rowb = m0 + wr*64 + i*16 + lg*4;
        #pragma unroll
        for (int r=0;r<4;r++){
          const int tok = rowb + r;
          const int b_ = tok>>9, tl = tok&511;
          const int jt = tl>>6, jn = (tl>>4)&3, lck = tl&15;
          kp[((((size_t)(b_*8+h_)*8 + jt)*4 + jn)*2 + kk)*512
             + (lgk*16 + lck)*8 + e] = f2bf(acc[i][j][r] + bs);
        }
      }
    }
  } else {
    // V fragment-packed: ushort4 stores, wave-coalesced (512B units).
    #pragma unroll
    for (int j=0;j<4;j++){
      const int col = n0 + wc*64 + j*16 + lc;
      const float bs = bias[col];
      const int h_ = col>>6, dn = (col>>4)&3, lcv = col&15;
      #pragma unroll
      for (int i=0;i<4;i++){
        const int rowb = m0 + wr*64 + i*16 + lg*4;
        const int b_ = rowb>>9, tl = rowb&511;
        const int jt = tl>>6, kk = (tl>>5)&1, lgv = (tl>>3)&3, e0 = tl&7;
        *(ushort4*)&vp[((((size_t)(b_*8+h_)*8 + jt)*2 + kk)*4 + dn)*512
                       + (lgv*16 + lcv)*8 + e0] =
            make_ushort4(f2bf(acc[i][j][0]+bs), f2bf(acc[i][j][1]+bs),
                         f2bf(acc[i][j][2]+bs), f2bf(acc[i][j][3]+bs));
      }
    }
  }
}

// ---------------------------------------------------------------------------
// Flash attention, round-18: KVBLK=128 (4 j-steps instead of 8). Halves the
// per-step serial softmax chains (tmax fold + 2 ds_bpermute shuffles + exp +
// rescale) that the r3-r17 null results isolated as the wall. Single stream
// (r7's 2-stream was null; frees 16+ VGPR). kp/vp/biasp layouts unchanged —
// fragment indices are linear in the widened step. Bias regs processed in
// halves to cap live VGPR (~110).
// ---------------------------------------------------------------------------
__global__ __launch_bounds__(512,4) void attn_kernel(
    const uint16_t* __restrict__ q,     // [NTOK][HID] bf16, scaled 0.125*log2e
    const uint16_t* __restrict__ kp,    // fragment-packed K
    const uint16_t* __restrict__ vp,    // fragment-packed V
    const uint32_t* __restrict__ biasp, // [16][32][8][64][16] packed
    const float*    __restrict__ semb,  // [10][8] f32
    const float*    __restrict__ ew,    // [8]
    const float*    __restrict__ eb,    // [8]
    uint16_t* __restrict__ out)         // [NTOK][HID] bf16
{
  __shared__ float sp_rep[NHEAD][64][11];    // (semb+eb)*log2e, per-lane copy
  __shared__ uint16_t plds[NHEAD][16*128];   // P tile 16 x 128, swizzled rows
  const int b  = blockIdx.y;
  const int it = blockIdx.x;
  const int i0 = it*16;
  const int t  = threadIdx.x;
  const int h  = t>>6, l = t&63, lg = l>>4, lc = l&15;
  for (int i = t; i < NHEAD*64*MAXD; i += 512){
    const int hh = i / (64*MAXD), rem = i % (64*MAXD);
    const int a = rem / MAXD, d = rem % MAXD;
    sp_rep[hh][a][d] = (semb[d*NHEAD + hh] + eb[hh]) * LOG2E;
  }
  __syncthreads();
  const float ewf = ew[h] * LOG2E;
  const float* spl = &sp_rep[h][l][0];
  char* pb = (char*)&plds[h][0] + lc*256;     // row i=lc, 256B rows
  const int swz = (lc&7)<<4;                  // XOR swizzle (16B granular)

  short8 qf[2];
  #pragma unroll
  for (int kk=0;kk<2;kk++)
    qf[kk] = *(const short8*)&q[(size_t)(b*SEQ + i0 + lc)*HID + h*HD + kk*32 + lg*8];

  const uint4* bp = (const uint4*)(biasp + (((size_t)b*32 + it)*8)*64*16);
  const uint16_t* kpb = kp + (size_t)(b*8+h)*8*4*2*512 + l*8;
  const uint16_t* vpb = vp + (size_t)(b*8+h)*8*2*4*512 + l*8;

  float mrun = -1e30f;
  float lrun = 0.f;
  f32x4 oacc[4];
  #pragma unroll
  for (int dn=0;dn<4;dn++){ f32x4 z={0.f,0.f,0.f,0.f}; oacc[dn]=z; }

  #pragma unroll
  for (int jt128=0; jt128<4; ++jt128){
    // ---- S^T = K @ Q^T over 128 j: st[jnn], j = jt128*128 + jnn*16 + ... --
    f32x4 st[8];
    #pragma unroll
    for (int jnn=0;jnn<8;jnn++){ f32x4 z={0.f,0.f,0.f,0.f}; st[jnn]=z; }
    __builtin_amdgcn_s_setprio(1);
    #pragma unroll
    for (int jnn=0;jnn<8;jnn++){
      #pragma unroll
      for (int kk=0;kk<2;kk++){
        short8 kf = *(const short8*)&kpb[(size_t)((jt128*8 + jnn)*2 + kk)*512];
        st[jnn] = MFMA16(kf, qf[kk], st[jnn]);
      }
    }
    __builtin_amdgcn_s_setprio(0);
    // ---- bias + mask (log2 domain) in two register-halves; tile max --------
    float tmax = -1e30f;
    #pragma unroll
    for (int half=0; half<2; ++half){
      uint32_t uw[16];
      {
        const uint4* bq_ = bp + ((jt128*2 + half)*64 + l)*4;
        *(uint4*)&uw[0]  = bq_[0];
        *(uint4*)&uw[4]  = bq_[1];
        *(uint4*)&uw[8]  = bq_[2];
        *(uint4*)&uw[12] = bq_[3];
      }
      #pragma unroll
      for (int jn=0;jn<4;jn++){
        const int jnn = half*4 + jn;
        #pragma unroll
        for (int r=0;r<4;r++){
          const uint32_t u = uw[jn*4+r];
          float sv = st[jnn][r] + spl[u & 0xFFu]
                   + bf2f((uint16_t)(u >> 16))*ewf;
          if (u & 0x100u) sv = -1e30f;
          st[jnn][r] = sv;
          tmax = fmaxf(tmax, sv);
        }
      }
    }
    // ---- online softmax (log2 domain), one chain per 128-j step ------------
    {
      float tm = fmaxf(tmax, __shfl_xor(tmax, 16, 64));
      tm = fmaxf(tm, __shfl_xor(tm, 32, 64));
      float mnew = fmaxf(mrun, tm);
      mnew = fmaxf(mnew, -1e20f);           // guard: fully-masked tile
      const float c = __builtin_amdgcn_exp2f(mrun - mnew);
      mrun = mnew;
      float lsum = 0.f;
      #pragma unroll
      for (int jnn=0;jnn<8;jnn++){
        float p0 = __builtin_amdgcn_exp2f(st[jnn][0]-mnew);
        float p1 = __builtin_amdgcn_exp2f(st[jnn][1]-mnew);
        float p2 = __builtin_amdgcn_exp2f(st[jnn][2]-mnew);
        float p3 = __builtin_amdgcn_exp2f(st[jnn][3]-mnew);
        lsum += (p0+p1)+(p2+p3);
        *(ushort4*)(pb + ((jnn*32 + lg*8) ^ swz)) =
            make_ushort4(f2bf_rtz(p0), f2bf_rtz(p1),
                         f2bf_rtz(p2), f2bf_rtz(p3));
      }
      lrun = lrun*c + lsum;
      #pragma unroll
      for (int r=0;r<4;r++){
        const float cr = __shfl(c, lg*4+r, 64);
        #pragma unroll
        for (int dn=0;dn<4;dn++) oacc[dn][r] *= cr;
      }
    }
    // ---- PV: 4 k-slices of 32 — V loads contiguous 1KB per inst ------------
    __builtin_amdgcn_s_setprio(1);
    #pragma unroll
    for (int ks=0;ks<4;ks++){
      short8 pa = *(const short8*)(pb + ((ks*64 + lg*16) ^ swz));
      #pragma unroll
      for (int dn=0;dn<4;dn++){
        short8 vb = *(const short8*)&vpb[(size_t)((jt128*4 + ks)*4 + dn)*512];
        oacc[dn] = MFMA16(pa, vb, oacc[dn]);
      }
    }
    __builtin_amdgcn_s_setprio(0);
  }
  // ---- finalize: reduce row sum across lane groups, store bf16 -------------
  {
    float ls = lrun;
    ls += __shfl_xor(ls, 16, 64);
    ls += __shfl_xor(ls, 32, 64);
    const float inv = 1.f/ls;
    #pragma unroll
    for (int r=0;r<4;r++){
      const float ir = __shfl(inv, lg*4+r, 64);
      const size_t orow = ((size_t)b*SEQ + i0 + lg*4 + r)*HID;
      #pragma unroll
      for (int dn=0;dn<4;dn++)
        out[orow + h*HD + dn*16 + lc] = f2bf(oacc[dn][r]*ir);
    }
  }
}

// ---------------------------------------------------------------------------
// LayerNorm with fused residual: u = a(bf16) + b(bf16); LN(u) -> opt f32 +
// opt bf16.
// ---------------------------------------------------------------------------
__global__ __launch_bounds__(256) void ln_kernel(
    const uint16_t* __restrict__ a, const uint16_t* __restrict__ bsrc,
    const float* __restrict__ g, const float* __restrict__ bb,
    float* __restrict__ of, uint16_t* __restrict__ ob)
{
  const int row = blockIdx.x*4 + (threadIdx.x>>6);
  const int l = threadIdx.x & 63;
  const int c0 = l*8;
  const uint16_t* ar = a    + (size_t)row*HID + c0;
  const uint16_t* br = bsrc + (size_t)row*HID + c0;
  short8 av = *(const short8*)ar;
  short8 bv = *(const short8*)br;
  float u[8];
  #pragma unroll
  for (int e=0;e<8;e++)
    u[e] = bf2f((uint16_t)av[e]) + bf2f((uint16_t)bv[e]);
  float s=0.f, ss=0.f;
  #pragma unroll
  for (int e=0;e<8;e++){ s += u[e]; ss += u[e]*u[e]; }
  #pragma unroll
  for (int off=32; off>=1; off>>=1){
    s  += __shfl_xor(s,  off, 64);
    ss += __shfl_xor(ss, off, 64);
  }
  const float mu  = s*(1.f/512.f);
  const float inv = rsqrtf(ss*(1.f/512.f) - mu*mu + 1e-5f);
  float4 g0 = *(const float4*)(g + c0),  g1 = *(const float4*)(g + c0 + 4);
  float4 q0 = *(const float4*)(bb + c0), q1 = *(const float4*)(bb + c0 + 4);
  float y[8];
  y[0]=(u[0]-mu)*inv*g0.x+q0.x; y[1]=(u[1]-mu)*inv*g0.y+q0.y;
  y[2]=(u[2]-mu)*inv*g0.z+q0.z; y[3]=(u[3]-mu)*inv*g0.w+q0.w;
  y[4]=(u[4]-mu)*inv*g1.x+q1.x; y[5]=(u[5]-mu)*inv*g1.y+q1.y;
  y[6]=(u[6]-mu)*inv*g1.z+q1.z; y[7]=(u[7]-mu)*inv*g1.w+q1.w;
  if (of){
    float* orow = of + (size_t)row*HID + c0;
    *(float4*)orow     = make_float4(y[0],y[1],y[2],y[3]);
    *(float4*)(orow+4) = make_float4(y[4],y[5],y[6],y[7]);
  }
  if (ob){
    uint16_t* brow = ob + (size_t)row*HID + c0;
    *(ushort4*)brow     = make_ushort4(f2bf(y[0]),f2bf(y[1]),f2bf(y[2]),f2bf(y[3]));
    *(ushort4*)(brow+4) = make_ushort4(f2bf(y[4]),f2bf(y[5]),f2bf(y[6]),f2bf(y[7]));
  }
}

// ---------------------------------------------------------------------------
extern "C" void kernel_launch(void* const* d_in, const int* in_sizes, int n_in,
                              void* d_out, int out_size, void* d_ws, size_t ws_size,
                              hipStream_t stream)
{
  (void)in_sizes; (void)n_in; (void)out_size; (void)ws_size;
  const float* x    = (const float*)d_in[0];
  const int*   dist = (const int*)  d_in[1];
  const float* edge = (const float*)d_in[2];
  const int*   mask = (const int*)  d_in[3];
  const float* Wq = (const float*)d_in[4];
  const float* bq = (const float*)d_in[5];
  const float* Wk = (const float*)d_in[6];
  const float* bk = (const float*)d_in[7];
  const float* Wv = (const float*)d_in[8];
  const float* bv = (const float*)d_in[9];
  const float* Wo = (const float*)d_in[10];
  const float* bo = (const float*)d_in[11];
  const float* semb = (const float*)d_in[12];
  const float* ew   = (const float*)d_in[13];
  const float* eb   = (const float*)d_in[14];
  const float* ln1g = (const float*)d_in[15];
  const float* ln1b = (const float*)d_in[16];
  const float* ln2g = (const float*)d_in[17];
  const float* ln2b = (const float*)d_in[18];
  const float* W1 = (const float*)d_in[19];
  const float* b1 = (const float*)d_in[20];
  const float* W2 = (const float*)d_in[21];
  const float* b2 = (const float*)d_in[22];

  // workspace layout (~94 MB; biasp overlaid by tb16 after attn)
  char* ws = (char*)d_ws;
  uint16_t* xb16  = (uint16_t*)ws;                        // [NTOK][HID] bf16
  uint16_t* qbuf  = xb16  + (size_t)NTOK*HID;
  uint16_t* kpbuf = qbuf  + (size_t)NTOK*HID;             // fragment-packed K
  uint16_t* vpbuf = kpbuf + (size_t)NTOK*HID;             // fragment-packed V
  uint16_t* aobuf = vpbuf + (size_t)NTOK*HID;
  uint16_t* f1buf = qbuf;                                 // aliases q/kp (33.5MB)
  uint32_t* biasp = (uint32_t*)(ws + (size_t)5*NTOK*HID*2); // 16.78 MB
  uint16_t* tb16  = (uint16_t*)biasp;                     // overlay: bias dead
  uint16_t* t2b16 = tb16;                                 // alias (t dead after LN1)
  uint16_t* hb16  = (uint16_t*)((char*)biasp + (size_t)NTOK*HID*4); // bf16 8.4MB
  uint16_t* wt    = hb16 + (size_t)NTOK*HID;
  uint16_t* wtq = wt;
  uint16_t* wtk = wtq + 512*512;
  uint16_t* wtv = wtk + 512*512;
  uint16_t* wto = wtv + 512*512;
  uint16_t* wt1 = wto + 512*512;      // [2048][512]
  uint16_t* wt2 = wt1 + 512*2048;     // [512][2048]

  prep_kernel<<<7168, 256, 0, stream>>>(x, xb16, Wq,Wk,Wv,Wo,W1,W2,
                                        wtq,wtk,wtv,wto,wt1,wt2);

  // merged qkv GEMM + bias pack (block roles interleaved via flat id)
  qkv_pack<<<dim3(64,4,4), 256, 0, stream>>>(xb16, wtq,wtk,wtv, bq,bk,bv,
                                             qbuf, kpbuf, vpbuf,
                                             dist, edge, mask, biasp);

  attn_kernel<<<dim3(32,16), 512, 0, stream>>>(qbuf, kpbuf, vpbuf, biasp,
                                               semb, ew, eb, aobuf);

  // Wo: 64x128 tiles
  gemm_bt<EPI_BF16,64,128><<<dim3(128,4), 256, 0, stream>>>(aobuf, wto, bo, tb16, NTOK, HID, HID);

  ln_kernel<<<2048, 256, 0, stream>>>(tb16, xb16, ln1g, ln1b, nullptr, hb16);

  gemm_bt<EPI_RELU,128,128><<<dim3(64,16), 256, 0, stream>>>(hb16, wt1, b1, f1buf, NTOK, 2048, HID);

  // FFN2: 64x128 tiles
  gemm_bt<EPI_BF16,64,128><<<dim3(128,4), 256, 0, stream>>>(f1buf, wt2, b2, t2b16, NTOK, HID, 2048);

  ln_kernel<<<2048, 256, 0, stream>>>(t2b16, hb16, ln2g, ln2b, (float*)d_out, nullptr);
}

// Round 19
// 152.710 us; speedup vs baseline: 1.0124x; 1.0124x over previous
//
#include <hip/hip_runtime.h>
#include <stdint.h>
#include <stddef.h>

// Problem constants
#define SEQ   512
#define HID   512
#define NHEAD 8
#define HD    64
#define NBATCH 16
#define NTOK  8192      // NBATCH*SEQ
#define MAXD  10
#define LOG2E 1.4426950408889634f

typedef __attribute__((ext_vector_type(8))) short short8;
typedef __attribute__((ext_vector_type(4))) float f32x4;

typedef __attribute__((address_space(3))) void        as3_void;
typedef const __attribute__((address_space(1))) void  as1_cvoid;

#define MFMA16(a,b,c) __builtin_amdgcn_mfma_f32_16x16x32_bf16((a),(b),(c),0,0,0)

__device__ __forceinline__ float bf2f(uint16_t u){ return __uint_as_float(((uint32_t)u)<<16); }
__device__ __forceinline__ uint16_t f2bf(float f){
  uint32_t i = __float_as_uint(f);
  return (uint16_t)((i + 0x7fffu + ((i>>16)&1u)) >> 16);
}
// truncating bf16 (P-pack only: P in (0,1], denominator exact -> bias < 0.4%)
__device__ __forceinline__ uint16_t f2bf_rtz(float f){
  return (uint16_t)(__float_as_uint(f) >> 16);
}

enum { EPI_BF16=0, EPI_F32=3, EPI_RELU=4 };

// ---------------------------------------------------------------------------
// prep: weight transpose+convert (blocks 0..3071) and x fp32->bf16
// (blocks 3072..7167) merged into one launch.
// ---------------------------------------------------------------------------
__global__ __launch_bounds__(256) void prep_kernel(
    const float* __restrict__ x, uint16_t* __restrict__ xb,
    const float* __restrict__ Wq, const float* __restrict__ Wk,
    const float* __restrict__ Wv, const float* __restrict__ Wo,
    const float* __restrict__ W1, const float* __restrict__ W2,
    uint16_t* __restrict__ tq, uint16_t* __restrict__ tk,
    uint16_t* __restrict__ tv, uint16_t* __restrict__ to_,
    uint16_t* __restrict__ t1, uint16_t* __restrict__ t2)
{
  int id = blockIdx.x;
  if (id >= 3072){                       // ---- f2bf part ----
    int i = (id-3072)*256 + threadIdx.x;
    if (i < NTOK*HID/4){
      float4 v = *(const float4*)(x + (size_t)i*4);
      *(ushort4*)(xb + (size_t)i*4) =
          make_ushort4(f2bf(v.x), f2bf(v.y), f2bf(v.z), f2bf(v.w));
    }
    return;
  }
  // ---- transpose part ----
  __shared__ uint16_t tile[32][33];
  const float* in; uint16_t* out; int R, C, tx, ty;
  if (id < 1024) {
    int m = id >> 8, loc = id & 255;
    in  = (m==0)?Wq:(m==1)?Wk:(m==2)?Wv:Wo;
    out = (m==0)?tq:(m==1)?tk:(m==2)?tv:to_;
    R = 512; C = 512; ty = loc>>4; tx = loc&15;
  } else if (id < 2048) {
    int loc = id-1024; in=W1; out=t1; R=512; C=2048; ty=loc>>6; tx=loc&63;
  } else {
    int loc = id-2048; in=W2; out=t2; R=2048; C=512; ty=loc>>4; tx=loc&15;
  }
  int bx = tx*32, by = ty*32;
  int lx = threadIdx.x & 31, ly = threadIdx.x >> 5;   // 32x8
  #pragma unroll
  for (int i=ly; i<32; i+=8) tile[i][lx] = f2bf(in[(size_t)(by+i)*C + bx+lx]);
  __syncthreads();
  #pragma unroll
  for (int i=ly; i<32; i+=8) out[(size_t)(bx+i)*R + by+lx] = tile[lx][i];
}

// ---------------------------------------------------------------------------
// GEMM mainloop — 2-phase double-buffer; T2 swizzle (rule #21).
// ---------------------------------------------------------------------------
template<int BM, int BN>
__device__ __forceinline__ void gemm_tile_mainloop(
    const uint16_t* __restrict__ A, const uint16_t* __restrict__ Bt,
    int K, int m0, int n0, uint16_t* lA, uint16_t* lB,
    f32x4 acc[4][(BM==128)?4:((BN==128)?2:1)])
{
  constexpr int NJ  = (BM==128)?4:((BN==128)?2:1);
  constexpr int ARD = BM/32;
  constexpr int BRD = BN/32;
  const int t = threadIdx.x;
  const int w = t>>6, l = t&63;
  const int lg = l>>4, lc = l&15;
  const int wr = (BM==128)?(w>>1):0;
  const int wc = (BM==128)?(w&1):w;
  const int swz = lc & 7;                  // read-side chunk XOR
  const int kSteps = K>>6;

  auto stage = [&](int kt, int buf){
    const int k0 = kt<<6;
    #pragma unroll
    for (int rd=0; rd<ARD; ++rd){
      const int e   = rd*2048 + t*8;
      const int row = e>>6;
      const int col = (((e>>3)&7) ^ (row&7))*8;   // inverse-swizzled source
      const uint16_t* ga = A + (size_t)(m0+row)*K + (k0+col);
      char* la = (char*)(lA + buf*(BM*64)) + rd*4096 + w*1024;
      __builtin_amdgcn_global_load_lds((as1_cvoid*)ga, (as3_void*)la, 16, 0, 0);
    }
    #pragma unroll
    for (int rd=0; rd<BRD; ++rd){
      const int e   = rd*2048 + t*8;
      const int row = e>>6;
      const int col = (((e>>3)&7) ^ (row&7))*8;
      const uint16_t* gb = Bt + (size_t)(n0+row)*K + (k0+col);
      char* lb = (char*)(lB + buf*(BN*64)) + rd*4096 + w*1024;
      __builtin_amdgcn_global_load_lds((as1_cvoid*)gb, (as3_void*)lb, 16, 0, 0);
    }
  };

  auto compute = [&](const uint16_t* rA, const uint16_t* rB){
    #pragma unroll
    for (int kk=0; kk<2; ++kk){
      const int cc = (kk*4 + lg) ^ swz;      // swizzled read chunk
      short8 af[4], bfr[NJ];
      #pragma unroll
      for (int i=0;i<4;i++)
        af[i]  = *(const short8*)&rA[(wr*64 + i*16 + lc)*64 + cc*8];
      #pragma unroll
      for (int j=0;j<NJ;j++)
        bfr[j] = *(const short8*)&rB[(wc*16*NJ + j*16 + lc)*64 + cc*8];
      #pragma unroll
      for (int i=0;i<4;i++)
        #pragma unroll
        for (int j=0;j<NJ;j++)
          acc[i][j] = MFMA16(af[i], bfr[j], acc[i][j]);
    }
  };

  stage(0, 0);
  __syncthreads();                   // drain prologue loads
  int cur = 0;
  for (int kt=0; kt<kSteps; ++kt){
    if (kt+1 < kSteps) stage(kt+1, cur^1);   // issue next tile early
    compute(lA + cur*(BM*64), lB + cur*(BN*64));
    __syncthreads();                 // drains next-tile loads + read fence
    cur ^= 1;
  }
}

// Generic GEMM with epilogue template (bias fp32). Grid: x=m-tile, y=n-tile.
template<int EPI, int BM, int BN>
__global__ __launch_bounds__(256,2) void gemm_bt(
    const uint16_t* __restrict__ A, const uint16_t* __restrict__ Bt,
    const float* __restrict__ bias, void* __restrict__ outp,
    int M, int N, int K)
{
  constexpr int NJ = (BM==128)?4:((BN==128)?2:1);
  __shared__ uint16_t lA[2*BM*64];
  __shared__ uint16_t lB[2*BN*64];
  f32x4 acc[4][NJ];
  #pragma unroll
  for (int i=0;i<4;i++)
    #pragma unroll
    for (int j=0;j<NJ;j++){ f32x4 z = {0.f,0.f,0.f,0.f}; acc[i][j]=z; }
  const int m0 = blockIdx.x*BM, n0 = blockIdx.y*BN;
  gemm_tile_mainloop<BM,BN>(A, Bt, K, m0, n0, lA, lB, acc);

  const int t=threadIdx.x, w=t>>6, l=t&63, lg=l>>4, lc=l&15;
  const int wr=(BM==128)?(w>>1):0, wc=(BM==128)?(w&1):w;
  #pragma unroll
  for (int j=0;j<NJ;j++){
    const int col = n0 + wc*16*NJ + j*16 + lc;
    const float bs = bias[col];
    #pragma unroll
    for (int i=0;i<4;i++){
      const int rowb = m0 + wr*64 + i*16 + lg*4;
      #pragma unroll
      for (int r=0;r<4;r++){
        float v = acc[i][j][r] + bs;
        if constexpr (EPI==EPI_RELU)   v = fmaxf(v, 0.f);
        if constexpr (EPI==EPI_F32)
          ((float*)outp)[(size_t)(rowb+r)*N + col] = v;
        else
          ((uint16_t*)outp)[(size_t)(rowb+r)*N + col] = f2bf(v);
      }
    }
  }
}

// ---------------------------------------------------------------------------
// Fused QKV + bias-pack mega-kernel (r16). Grid (64,4,4) = 1024 blocks.
// Every 4th block packs dist/edge/mask (memory-bound role overlapping the
// MFMA-bound GEMM roles); remaining 768 = r14 qkv GEMM (128² dbuf tiles).
// ---------------------------------------------------------------------------
__global__ __launch_bounds__(256,2) void qkv_pack(
    const uint16_t* __restrict__ x,
    const uint16_t* __restrict__ wtq, const uint16_t* __restrict__ wtk,
    const uint16_t* __restrict__ wtv,
    const float* __restrict__ bq, const float* __restrict__ bk,
    const float* __restrict__ bv,
    uint16_t* __restrict__ qo, uint16_t* __restrict__ kp,
    uint16_t* __restrict__ vp,
    const int*   __restrict__ dist,  // [16][512][512]
    const float* __restrict__ edge,  // [16][512][512]
    const int*   __restrict__ mask,  // [16][512]
    uint32_t*    __restrict__ biasp) // [16][32][8][64][16]
{
  __shared__ char smem[2*2*128*64*2];   // 64 KB union (gemm dbuf / pack stage)
  const int t = threadIdx.x;
  const int flat = blockIdx.x + 64*(blockIdx.y + 4*blockIdx.z);

  if ((flat & 3) == 3){
    // ---------------- pack role: two (b,it) units ----------------
    int*   dl = (int*)smem;                       // [16][260]
    float* el = (float*)(smem + 16*260*4);        // [16][260]
    int*   ml = (int*)(smem + 2*16*260*4);        // [512]
    #define DL(r,c) dl[(r)*260+(c)]
    #define EL(r,c) el[(r)*260+(c)]
    #pragma unroll
    for (int u0=0; u0<2; ++u0){
      const int u  = (flat>>2)*2 + u0;
      const int b  = u>>5, it = u&31;
      __syncthreads();                  // protect smem reuse across units
      ml[t]     = mask[b*SEQ + t];
      ml[t+256] = mask[b*SEQ + t + 256];
      #pragma unroll
      for (int jh=0; jh<2; ++jh){
        if (jh) __syncthreads();        // protect stage reuse across halves
        {
          const int r  = t >> 4;
          const int c0 = (t & 15) * 16;
          const size_t g = ((size_t)b*SEQ + it*16 + r)*SEQ + jh*256 + c0;
          *(int4*)&DL(r,c0)      = *(const int4*)&dist[g];
          *(int4*)&DL(r,c0+4)    = *(const int4*)&dist[g+4];
          *(int4*)&DL(r,c0+8)    = *(const int4*)&dist[g+8];
          *(int4*)&DL(r,c0+12)   = *(const int4*)&dist[g+12];
          *(float4*)&EL(r,c0)    = *(const float4*)&edge[g];
          *(float4*)&EL(r,c0+4)  = *(const float4*)&edge[g+4];
          *(float4*)&EL(r,c0+8)  = *(const float4*)&edge[g+8];
          *(float4*)&EL(r,c0+12) = *(const float4*)&edge[g+12];
        }
        __syncthreads();
        {
          const int i   = t & 15;
          const int j0p = (t >> 4) * 16;        // 16 consecutive j: one jn
          const int jn  = (j0p >> 4) & 3;
          const int jt  = jh*4 + (j0p >> 6);
          uint32_t wv[16];
          #pragma unroll
          for (int e=0; e<16; ++e){
            const int jl = j0p + e;
            const int jg = jh*256 + jl;
            const uint32_t d  = (uint32_t)DL(i,jl) & 0xFFu;
            const uint32_t mk = (ml[jg] ? 1u : 0u) << 8;
            wv[e] = ((uint32_t)f2bf(EL(i,jl)) << 16) | mk | d;
          }
          uint32_t* ob = biasp + ((((size_t)b*32 + it)*8 + jt)*64)*16;
          #pragma unroll
          for (int lgq=0; lgq<4; ++lgq)
            *(uint4*)&ob[(lgq*16 + i)*16 + jn*4] =
                make_uint4(wv[lgq*4], wv[lgq*4+1], wv[lgq*4+2], wv[lgq*4+3]);
        }
      }
    }
    #undef DL
    #undef EL
    return;
  }

  // ---------------- gemm role (r14 qkv) ----------------
  const int g  = (flat>>2)*3 + (flat&3);
  const int m0 = (g & 63) * 128;
  const int n0 = ((g >> 6) & 3) * 128;
  const int z  = g >> 8;
  uint16_t* lA = (uint16_t*)smem;
  uint16_t* lB = lA + 2*128*64;
  const uint16_t* Bt = (z==0)?wtq:(z==1)?wtk:wtv;
  const float*  bias = (z==0)?bq :(z==1)?bk :bv;
  f32x4 acc[4][4];
  #pragma unroll
  for (int i=0;i<4;i++)
    #pragma unroll
    for (int j=0;j<4;j++){ f32x4 zz = {0.f,0.f,0.f,0.f}; acc[i][j]=zz; }
  gemm_tile_mainloop<128,128>(x, Bt, HID, m0, n0, lA, lB, acc);

  const int w=t>>6, l=t&63, lg=l>>4, lc=l&15, wr=w>>1, wc=w&1;
  if (z==0){
    const float scale = 0.125f * LOG2E;   // 1/sqrt(HD) * log2(e)
    #pragma unroll
    for (int j=0;j<4;j++){
      const int col = n0 + wc*64 + j*16 + lc;
      const float bs = bias[col];
      #pragma unroll
      for (int i=0;i<4;i++){
        const int rowb = m0 + wr*64 + i*16 + lg*4;
        #pragma unroll
        for (int r=0;r<4;r++)
          qo[(size_t)(rowb+r)*HID + col] = f2bf((acc[i][j][r] + bs)*scale);
      }
    }
  } else if (z==1){
    // K fragment-packed: scalar stores, paid once.
    #pragma unroll
    for (int j=0;j<4;j++){
      const int col = n0 + wc*64 + j*16 + lc;
      const float bs = bias[col];
      const int h_ = col>>6, cm = col&63, kk = cm>>5, lgk = (cm>>3)&3, e = col&7;
      #pragma unroll
      for (int i=0;i<4;i++){
        const int rowb = m0 + wr*64 + i*16 + lg*4;
        #pragma unroll
        for (int r=0;r<4;r++){
          const int tok = rowb + r;
          const int b_ = tok>>9, tl = tok&511;
          const int jt = tl>>6, jn = (tl>>4)&3, lck = tl&15;
          kp[((((size_t)(b_*8+h_)*8 + jt)*4 + jn)*2 + kk)*512
             + (lgk*16 + lck)*8 + e] = f2bf(acc[i][j][r] + bs);
        }
      }
    }
  } else {
    // V fragment-packed: ushort4 stores, wave-coalesced (512B units).
    #pragma unroll
    for (int j=0;j<4;j++){
      const int col = n0 + wc*64 + j*16 + lc;
      const float bs = bias[col];
      const int h_ = col>>6, dn = (col>>4)&3, lcv = col&15;
      #pragma unroll
      for (int i=0;i<4;i++){
        const int rowb = m0 + wr*64 + i*16 + lg*4;
        const int b_ = rowb>>9, tl = rowb&511;
        const int jt = tl>>6, kk = (tl>>5)&1, lgv = (tl>>3)&3, e0 = tl&7;
        *(ushort4*)&vp[((((size_t)(b_*8+h_)*8 + jt)*2 + kk)*4 + dn)*512
                       + (lgv*16 + lcv)*8 + e0] =
            make_ushort4(f2bf(acc[i][j][0]+bs), f2bf(acc[i][j][1]+bs),
                         f2bf(acc[i][j][2]+bs), f2bf(acc[i][j][3]+bs));
      }
    }
  }
}

// ---------------------------------------------------------------------------
// Flash attention (r17 best): packed bias, frag-packed K/V, log2 softmax,
// XOR-swizzled plds, per-lane spl copies, truncating P-pack, 2-stream.
// ---------------------------------------------------------------------------
__global__ __launch_bounds__(512,4) void attn_kernel(
    const uint16_t* __restrict__ q,     // [NTOK][HID] bf16, scaled 0.125*log2e
    const uint16_t* __restrict__ kp,    // fragment-packed K
    const uint16_t* __restrict__ vp,    // fragment-packed V
    const uint32_t* __restrict__ biasp, // [16][32][8][64][16] packed
    const float*    __restrict__ semb,  // [10][8] f32
    const float*    __restrict__ ew,    // [8]
    const float*    __restrict__ eb,    // [8]
    uint16_t* __restrict__ out)         // [NTOK][HID] bf16
{
  __shared__ float sp_rep[NHEAD][64][11];     // (semb+eb)*log2e, per-lane copy
  __shared__ uint16_t plds[NHEAD][2][16*64];  // P tile, XOR-swizzled rows
  const int b  = blockIdx.y;
  const int it = blockIdx.x;
  const int i0 = it*16;
  const int t  = threadIdx.x;
  const int h  = t>>6, l = t&63, lg = l>>4, lc = l&15;
  for (int i = t; i < NHEAD*64*MAXD; i += 512){
    const int hh = i / (64*MAXD), rem = i % (64*MAXD);
    const int a = rem / MAXD, d = rem % MAXD;
    sp_rep[hh][a][d] = (semb[d*NHEAD + hh] + eb[hh]) * LOG2E;
  }
  __syncthreads();
  const float ewf = ew[h] * LOG2E;
  const float* spl = &sp_rep[h][l][0];
  char* pbase = (char*)&plds[h][0][0];
  const int swz = (lc&7)<<4;                  // XOR swizzle for row lc

  short8 qf[2];
  #pragma unroll
  for (int kk=0;kk<2;kk++)
    qf[kk] = *(const short8*)&q[(size_t)(b*SEQ + i0 + lc)*HID + h*HD + kk*32 + lg*8];

  const uint4* bp = (const uint4*)(biasp + (((size_t)b*32 + it)*8)*64*16);
  const uint16_t* kpb = kp + (size_t)(b*8+h)*8*4*2*512 + l*8;
  const uint16_t* vpb = vp + (size_t)(b*8+h)*8*2*4*512 + l*8;

  float mrun[2] = {-1e30f, -1e30f};
  float lrun[2] = {0.f, 0.f};
  f32x4 oacc[2][4];
  #pragma unroll
  for (int s=0;s<2;s++)
    #pragma unroll
    for (int dn=0;dn<4;dn++){ f32x4 z={0.f,0.f,0.f,0.f}; oacc[s][dn]=z; }

  #pragma unroll
  for (int p=0; p<4; ++p){
    #pragma unroll
    for (int s=0; s<2; ++s){
      const int jt = s*4 + p;
      // packed bias: 4 coalesced uint4 per lane
      uint32_t uw[16];
      {
        const uint4* bq_ = bp + (jt*64 + l)*4;
        *(uint4*)&uw[0]  = bq_[0];
        *(uint4*)&uw[4]  = bq_[1];
        *(uint4*)&uw[8]  = bq_[2];
        *(uint4*)&uw[12] = bq_[3];
      }
      // S^T = K @ Q^T — K loads are contiguous 1KB per inst
      f32x4 st[4];
      #pragma unroll
      for (int jn=0;jn<4;jn++){ f32x4 z={0.f,0.f,0.f,0.f}; st[jn]=z; }
      __builtin_amdgcn_s_setprio(1);
      #pragma unroll
      for (int jn=0;jn<4;jn++){
        #pragma unroll
        for (int kk=0;kk<2;kk++){
          short8 kf = *(const short8*)&kpb[(size_t)((jt*4 + jn)*2 + kk)*512];
          st[jn] = MFMA16(kf, qf[kk], st[jn]);
        }
      }
      __builtin_amdgcn_s_setprio(0);
      // bias + mask (log2 domain), tile max
      float tmax = -1e30f;
      #pragma unroll
      for (int jn=0;jn<4;jn++){
        #pragma unroll
        for (int r=0;r<4;r++){
          const uint32_t u = uw[jn*4+r];
          float sv = st[jn][r] + spl[u & 0xFFu]
                   + bf2f((uint16_t)(u >> 16))*ewf;
          if (u & 0x100u) sv = -1e30f;
          st[jn][r] = sv;
          tmax = fmaxf(tmax, sv);
        }
      }
      // online softmax (log2 domain), unconditional rescale
      {
        float tm = fmaxf(tmax, __shfl_xor(tmax, 16, 64));
        tm = fmaxf(tm, __shfl_xor(tm, 32, 64));
        float mnew = fmaxf(mrun[s], tm);
        mnew = fmaxf(mnew, -1e20f);           // guard: fully-masked tile
        const float c = __builtin_amdgcn_exp2f(mrun[s] - mnew);
        mrun[s] = mnew;
        float lsum = 0.f;
        char* pb = pbase + s*(16*64*2) + lc*128;
        #pragma unroll
        for (int jn=0;jn<4;jn++){
          float p0 = __builtin_amdgcn_exp2f(st[jn][0]-mnew);
          float p1 = __builtin_amdgcn_exp2f(st[jn][1]-mnew);
          float p2 = __builtin_amdgcn_exp2f(st[jn][2]-mnew);
          float p3 = __builtin_amdgcn_exp2f(st[jn][3]-mnew);
          lsum += (p0+p1)+(p2+p3);
          *(ushort4*)(pb + (((jn*16 + lg*4)*2) ^ swz)) =
              make_ushort4(f2bf_rtz(p0), f2bf_rtz(p1),
                           f2bf_rtz(p2), f2bf_rtz(p3));
        }
        lrun[s] = lrun[s]*c + lsum;
        #pragma unroll
        for (int r=0;r<4;r++){
          const float cr = __shfl(c, lg*4+r, 64);
          #pragma unroll
          for (int dn=0;dn<4;dn++) oacc[s][dn][r] *= cr;
        }
      }
    }
    // PV for both streams — V loads are contiguous 1KB per inst
    #pragma unroll
    for (int s=0; s<2; ++s){
      const int jt = s*4 + p;
      char* pb = pbase + s*(16*64*2) + lc*128;
      __builtin_amdgcn_s_setprio(1);
      #pragma unroll
      for (int kk=0;kk<2;kk++){
        short8 pa = *(const short8*)(pb + (((kk*32 + lg*8)*2) ^ swz));
        #pragma unroll
        for (int dn=0;dn<4;dn++){
          short8 vb = *(const short8*)&vpb[(size_t)((jt*2 + kk)*4 + dn)*512];
          oacc[s][dn] = MFMA16(pa, vb, oacc[s][dn]);
        }
      }
      __builtin_amdgcn_s_setprio(0);
    }
  }
  // ---- merge the two streams in-register, then finalize --------------------
  {
    const float mm = fmaxf(mrun[0], mrun[1]);
    const float c0 = __builtin_amdgcn_exp2f(mrun[0]-mm);
    const float c1 = __builtin_amdgcn_exp2f(mrun[1]-mm);
    float ls = lrun[0]*c0 + lrun[1]*c1;
    ls += __shfl_xor(ls, 16, 64);
    ls += __shfl_xor(ls, 32, 64);
    const float inv = 1.f/ls;
    #pragma unroll
    for (int r=0;r<4;r++){
      const float cr0 = __shfl(c0, lg*4+r, 64);
      const float cr1 = __shfl(c1, lg*4+r, 64);
      const float ir  = __shfl(inv, lg*4+r, 64);
      const size_t orow = ((size_t)b*SEQ + i0 + lg*4 + r)*HID;
      #pragma unroll
      for (int dn=0;dn<4;dn++)
        out[orow + h*HD + dn*16 + lc] =
            f2bf((oacc[0][dn][r]*cr0 + oacc[1][dn][r]*cr1)*ir);
    }
  }
}

// ---------------------------------------------------------------------------
// LayerNorm with fused residual: u = a(bf16) + b(bf16); LN(u) -> opt f32 +
// opt bf16.
// ---------------------------------------------------------------------------
__global__ __launch_bounds__(256) void ln_kernel(
    const uint16_t* __restrict__ a, const uint16_t* __restrict__ bsrc,
    const float* __restrict__ g, const float* __restrict__ bb,
    float* __restrict__ of, uint16_t* __restrict__ ob)
{
  const int row = blockIdx.x*4 + (threadIdx.x>>6);
  const int l = threadIdx.x & 63;
  const int c0 = l*8;
  const uint16_t* ar = a    + (size_t)row*HID + c0;
  const uint16_t* br = bsrc + (size_t)row*HID + c0;
  short8 av = *(const short8*)ar;
  short8 bv = *(const short8*)br;
  float u[8];
  #pragma unroll
  for (int e=0;e<8;e++)
    u[e] = bf2f((uint16_t)av[e]) + bf2f((uint16_t)bv[e]);
  float s=0.f, ss=0.f;
  #pragma unroll
  for (int e=0;e<8;e++){ s += u[e]; ss += u[e]*u[e]; }
  #pragma unroll
  for (int off=32; off>=1; off>>=1){
    s  += __shfl_xor(s,  off, 64);
    ss += __shfl_xor(ss, off, 64);
  }
  const float mu  = s*(1.f/512.f);
  const float inv = rsqrtf(ss*(1.f/512.f) - mu*mu + 1e-5f);
  float4 g0 = *(const float4*)(g + c0),  g1 = *(const float4*)(g + c0 + 4);
  float4 q0 = *(const float4*)(bb + c0), q1 = *(const float4*)(bb + c0 + 4);
  float y[8];
  y[0]=(u[0]-mu)*inv*g0.x+q0.x; y[1]=(u[1]-mu)*inv*g0.y+q0.y;
  y[2]=(u[2]-mu)*inv*g0.z+q0.z; y[3]=(u[3]-mu)*inv*g0.w+q0.w;
  y[4]=(u[4]-mu)*inv*g1.x+q1.x; y[5]=(u[5]-mu)*inv*g1.y+q1.y;
  y[6]=(u[6]-mu)*inv*g1.z+q1.z; y[7]=(u[7]-mu)*inv*g1.w+q1.w;
  if (of){
    float* orow = of + (size_t)row*HID + c0;
    *(float4*)orow     = make_float4(y[0],y[1],y[2],y[3]);
    *(float4*)(orow+4) = make_float4(y[4],y[5],y[6],y[7]);
  }
  if (ob){
    uint16_t* brow = ob + (size_t)row*HID + c0;
    *(ushort4*)brow     = make_ushort4(f2bf(y[0]),f2bf(y[1]),f2bf(y[2]),f2bf(y[3]));
    *(ushort4*)(brow+4) = make_ushort4(f2bf(y[4]),f2bf(y[5]),f2bf(y[6]),f2bf(y[7]));
  }
}

// ---------------------------------------------------------------------------
extern "C" void kernel_launch(void* const* d_in, const int* in_sizes, int n_in,
                              void* d_out, int out_size, void* d_ws, size_t ws_size,
                              hipStream_t stream)
{
  (void)in_sizes; (void)n_in; (void)out_size; (void)ws_size;
  const float* x    = (const float*)d_in[0];
  const int*   dist = (const int*)  d_in[1];
  const float* edge = (const float*)d_in[2];
  const int*   mask = (const int*)  d_in[3];
  const float* Wq = (const float*)d_in[4];
  const float* bq = (const float*)d_in[5];
  const float* Wk = (const float*)d_in[6];
  const float* bk = (const float*)d_in[7];
  const float* Wv = (const float*)d_in[8];
  const float* bv = (const float*)d_in[9];
  const float* Wo = (const float*)d_in[10];
  const float* bo = (const float*)d_in[11];
  const float* semb = (const float*)d_in[12];
  const float* ew   = (const float*)d_in[13];
  const float* eb   = (const float*)d_in[14];
  const float* ln1g = (const float*)d_in[15];
  const float* ln1b = (const float*)d_in[16];
  const float* ln2g = (const float*)d_in[17];
  const float* ln2b = (const float*)d_in[18];
  const float* W1 = (const float*)d_in[19];
  const float* b1 = (const float*)d_in[20];
  const float* W2 = (const float*)d_in[21];
  const float* b2 = (const float*)d_in[22];

  // workspace layout (~94 MB; biasp overlaid by tb16 after attn)
  char* ws = (char*)d_ws;
  uint16_t* xb16  = (uint16_t*)ws;                        // [NTOK][HID] bf16
  uint16_t* qbuf  = xb16  + (size_t)NTOK*HID;
  uint16_t* kpbuf = qbuf  + (size_t)NTOK*HID;             // fragment-packed K
  uint16_t* vpbuf = kpbuf + (size_t)NTOK*HID;             // fragment-packed V
  uint16_t* aobuf = vpbuf + (size_t)NTOK*HID;
  uint16_t* f1buf = qbuf;                                 // aliases q/kp (33.5MB)
  uint32_t* biasp = (uint32_t*)(ws + (size_t)5*NTOK*HID*2); // 16.78 MB
  uint16_t* tb16  = (uint16_t*)biasp;                     // overlay: bias dead
  uint16_t* t2b16 = tb16;                                 // alias (t dead after LN1)
  uint16_t* hb16  = (uint16_t*)((char*)biasp + (size_t)NTOK*HID*4); // bf16 8.4MB
  uint16_t* wt    = hb16 + (size_t)NTOK*HID;
  uint16_t* wtq = wt;
  uint16_t* wtk = wtq + 512*512;
  uint16_t* wtv = wtk + 512*512;
  uint16_t* wto = wtv + 512*512;
  uint16_t* wt1 = wto + 512*512;      // [2048][512]
  uint16_t* wt2 = wt1 + 512*2048;     // [512][2048]

  prep_kernel<<<7168, 256, 0, stream>>>(x, xb16, Wq,Wk,Wv,Wo,W1,W2,
                                        wtq,wtk,wtv,wto,wt1,wt2);

  // merged qkv GEMM + bias pack (block roles interleaved via flat id)
  qkv_pack<<<dim3(64,4,4), 256, 0, stream>>>(xb16, wtq,wtk,wtv, bq,bk,bv,
                                             qbuf, kpbuf, vpbuf,
                                             dist, edge, mask, biasp);

  attn_kernel<<<dim3(32,16), 512, 0, stream>>>(qbuf, kpbuf, vpbuf, biasp,
                                               semb, ew, eb, aobuf);

  // Wo: 64x128 tiles
  gemm_bt<EPI_BF16,64,128><<<dim3(128,4), 256, 0, stream>>>(aobuf, wto, bo, tb16, NTOK, HID, HID);

  ln_kernel<<<2048, 256, 0, stream>>>(tb16, xb16, ln1g, ln1b, nullptr, hb16);

  gemm_bt<EPI_RELU,128,128><<<dim3(64,16), 256, 0, stream>>>(hb16, wt1, b1, f1buf, NTOK, 2048, HID);

  // FFN2: 64x128 tiles
  gemm_bt<EPI_BF16,64,128><<<dim3(128,4), 256, 0, stream>>>(f1buf, wt2, b2, t2b16, NTOK, HID, 2048);

  ln_kernel<<<2048, 256, 0, stream>>>(t2b16, hb16, ln2g, ln2b, (float*)d_out, nullptr);
}